// Round 7
// baseline (3042.851 us; speedup 1.0000x reference)
//
#include <hip/hip_runtime.h>
#include <hip/hip_bf16.h>
#include <stdint.h>

#define EMB 768
#define HEADS 12
#define BATCH 8
#define SEQ 1024
#define HD 64
#define M_ROWS (BATCH * SEQ)   /* 8192 */
#define QKV_COLS (3 * EMB)     /* 2304 */

typedef __attribute__((ext_vector_type(4))) float f32x4;

__device__ __forceinline__ unsigned short f2bf(float x) {
    union { float f; unsigned u; } v; v.f = x;
    unsigned r = v.u + 0x7FFFu + ((v.u >> 16) & 1u);
    return (unsigned short)(r >> 16);
}
__device__ __forceinline__ float bf2f(unsigned short h) {
    union { unsigned u; float f; } v; v.u = ((unsigned)h) << 16;
    return v.f;
}

// ---------------------------------------------------------------------------
// QKV GEMM, pure fp32 vector-FMA. C = X[rows x 768] @ W[768 x 2304] + b.
// 128x128 tile, 256 threads, 8x8 outputs/thread, K-step 16.
// Epilogue de-interleaves col c = 192h + 3d + which -> Qf/Kf (fp32), Vb (bf16).
// ---------------------------------------------------------------------------
__global__ __launch_bounds__(256, 2)
void gemm_qkv_f32(const float* __restrict__ X, const float* __restrict__ W,
                  const float* __restrict__ bias,
                  float* __restrict__ Qf, float* __restrict__ Kf,
                  unsigned short* __restrict__ Vb)
{
    __shared__ float As[128][17];    // [m][k], pad 16->17
    __shared__ float Bs[16][132];    // [k][n], pad 128->132

    const int tid = threadIdx.x;
    const int tx = tid & 15, ty = tid >> 4;
    const int m0 = blockIdx.y * 128, c0 = blockIdx.x * 128;

    float acc[8][8];
    #pragma unroll
    for (int i = 0; i < 8; ++i)
        #pragma unroll
        for (int j = 0; j < 8; ++j) acc[i][j] = 0.f;

    for (int k0 = 0; k0 < EMB; k0 += 16) {
        #pragma unroll
        for (int p = 0; p < 8; ++p) {           // As: 128x16 = 2048 floats
            int idx = (p << 8) + tid;
            int r = idx >> 4, kk = idx & 15;
            As[r][kk] = X[(size_t)(m0 + r) * EMB + k0 + kk];
        }
        #pragma unroll
        for (int p = 0; p < 8; ++p) {           // Bs: 16x128 = 2048 floats
            int idx = (p << 8) + tid;
            int kk = idx >> 7, cc = idx & 127;
            Bs[kk][cc] = W[(size_t)(k0 + kk) * QKV_COLS + c0 + cc];
        }
        __syncthreads();

        #pragma unroll
        for (int kk = 0; kk < 16; ++kk) {
            float a[8], b[8];
            #pragma unroll
            for (int i = 0; i < 8; ++i) a[i] = As[ty * 8 + i][kk];
            *reinterpret_cast<f32x4*>(&b[0]) = *reinterpret_cast<const f32x4*>(&Bs[kk][tx * 8]);
            *reinterpret_cast<f32x4*>(&b[4]) = *reinterpret_cast<const f32x4*>(&Bs[kk][tx * 8 + 4]);
            #pragma unroll
            for (int i = 0; i < 8; ++i)
                #pragma unroll
                for (int j = 0; j < 8; ++j)
                    acc[i][j] = fmaf(a[i], b[j], acc[i][j]);
        }
        __syncthreads();
    }

    #pragma unroll
    for (int j = 0; j < 8; ++j) {
        const int colg = c0 + tx * 8 + j;
        const float bv = bias[colg];
        const int which = colg % 3;
        const int h  = colg / 192;
        const int dd = (colg % 192) / 3;
        #pragma unroll
        for (int i = 0; i < 8; ++i) {
            const int rowg = m0 + ty * 8 + i;
            const float val = acc[i][j] + bv;
            const int bi = rowg >> 10, ni = rowg & (SEQ - 1);
            const size_t oidx = (((size_t)bi * HEADS + h) * SEQ + ni) * HD + dd;
            if (which == 0)      Qf[oidx] = val;
            else if (which == 1) Kf[oidx] = val;
            else                 Vb[oidx] = f2bf(val);
        }
    }
}

// ---------------------------------------------------------------------------
// Attention, pure fp32, one thread per q-row. Online softmax over 1024 keys.
// Scores UNSCALED (softmax first); /sqrt(768) folded into output scale.
// ---------------------------------------------------------------------------
__global__ __launch_bounds__(64, 2)
void attn_f32(const float* __restrict__ Qf, const float* __restrict__ Kf,
              const unsigned short* __restrict__ Vb,
              unsigned short* __restrict__ Ob)
{
    const int gid = blockIdx.x * 64 + threadIdx.x;
    const int bh = gid >> 10, n = gid & (SEQ - 1);
    const int b = bh / HEADS, h = bh % HEADS;

    const float* Qr = Qf + ((size_t)bh * SEQ + n) * HD;
    const float* Kb = Kf + (size_t)bh * SEQ * HD;
    const unsigned short* Vbb = Vb + (size_t)bh * SEQ * HD;

    float q[HD];
    #pragma unroll
    for (int d4 = 0; d4 < 16; ++d4) {
        f32x4 v = *reinterpret_cast<const f32x4*>(Qr + d4 * 4);
        q[d4 * 4 + 0] = v[0]; q[d4 * 4 + 1] = v[1];
        q[d4 * 4 + 2] = v[2]; q[d4 * 4 + 3] = v[3];
    }

    float o[HD];
    #pragma unroll
    for (int d = 0; d < HD; ++d) o[d] = 0.f;
    float m = -1.0e30f, l = 0.f;

    for (int key = 0; key < SEQ; ++key) {
        const float* Kr = Kb + (size_t)key * HD;
        float dot = 0.f;
        #pragma unroll
        for (int d4 = 0; d4 < 16; ++d4) {
            f32x4 kv = *reinterpret_cast<const f32x4*>(Kr + d4 * 4);
            dot = fmaf(q[d4 * 4 + 0], kv[0], dot);
            dot = fmaf(q[d4 * 4 + 1], kv[1], dot);
            dot = fmaf(q[d4 * 4 + 2], kv[2], dot);
            dot = fmaf(q[d4 * 4 + 3], kv[3], dot);
        }
        float p;
        if (dot <= m) {
            p = __expf(dot - m);
        } else {
            const float corr = __expf(m - dot);   // exp(-huge)=0 on first key
            #pragma unroll
            for (int d = 0; d < HD; ++d) o[d] *= corr;
            l *= corr;
            m = dot;
            p = 1.f;
        }
        l += p;
        const unsigned short* Vr = Vbb + (size_t)key * HD;
        #pragma unroll
        for (int d8 = 0; d8 < 8; ++d8) {
            uint4 vv = *reinterpret_cast<const uint4*>(Vr + d8 * 8);
            const unsigned short* pv = reinterpret_cast<const unsigned short*>(&vv);
            #pragma unroll
            for (int j = 0; j < 8; ++j)
                o[d8 * 8 + j] = fmaf(p, bf2f(pv[j]), o[d8 * 8 + j]);
        }
    }

    const float rs = 0.036084391824351615f;  // 1/sqrt(768)
    const float sc = rs / l;
    unsigned short* Or = Ob + ((size_t)b * SEQ + n) * EMB + h * HD;
    #pragma unroll
    for (int d = 0; d < HD; ++d)
        Or[d] = f2bf(o[d] * sc);
}

// ---------------------------------------------------------------------------
// Proj GEMM, fp32 compute: Ob bf16 [8192x768] @ W_proj fp32 [768x768] + b
// -> *** fp32 *** d_out (the reference's output dtype is float32).
// ---------------------------------------------------------------------------
__global__ __launch_bounds__(256, 2)
void gemm_proj_f32(const unsigned short* __restrict__ A, const float* __restrict__ W,
                   const float* __restrict__ bias, float* __restrict__ Out)
{
    __shared__ float As[128][17];
    __shared__ float Bs[16][132];

    const int tid = threadIdx.x;
    const int tx = tid & 15, ty = tid >> 4;
    const int m0 = blockIdx.y * 128, c0 = blockIdx.x * 128;

    float acc[8][8];
    #pragma unroll
    for (int i = 0; i < 8; ++i)
        #pragma unroll
        for (int j = 0; j < 8; ++j) acc[i][j] = 0.f;

    for (int k0 = 0; k0 < EMB; k0 += 16) {
        #pragma unroll
        for (int p = 0; p < 8; ++p) {
            int idx = (p << 8) + tid;
            int r = idx >> 4, kk = idx & 15;
            As[r][kk] = bf2f(A[(size_t)(m0 + r) * EMB + k0 + kk]);
        }
        #pragma unroll
        for (int p = 0; p < 8; ++p) {
            int idx = (p << 8) + tid;
            int kk = idx >> 7, cc = idx & 127;
            Bs[kk][cc] = W[(size_t)(k0 + kk) * EMB + c0 + cc];
        }
        __syncthreads();

        #pragma unroll
        for (int kk = 0; kk < 16; ++kk) {
            float a[8], b[8];
            #pragma unroll
            for (int i = 0; i < 8; ++i) a[i] = As[ty * 8 + i][kk];
            *reinterpret_cast<f32x4*>(&b[0]) = *reinterpret_cast<const f32x4*>(&Bs[kk][tx * 8]);
            *reinterpret_cast<f32x4*>(&b[4]) = *reinterpret_cast<const f32x4*>(&Bs[kk][tx * 8 + 4]);
            #pragma unroll
            for (int i = 0; i < 8; ++i)
                #pragma unroll
                for (int j = 0; j < 8; ++j)
                    acc[i][j] = fmaf(a[i], b[j], acc[i][j]);
        }
        __syncthreads();
    }

    #pragma unroll
    for (int j = 0; j < 8; ++j) {
        const int colg = c0 + tx * 8 + j;
        const float bv = bias[colg];
        #pragma unroll
        for (int i = 0; i < 8; ++i) {
            const int rowg = m0 + ty * 8 + i;
            Out[(size_t)rowg * EMB + colg] = acc[i][j] + bv;
        }
    }
}

// ---------------------------------------------------------------------------
extern "C" void kernel_launch(void* const* d_in, const int* in_sizes, int n_in,
                              void* d_out, int out_size, void* d_ws, size_t ws_size,
                              hipStream_t stream)
{
    const float* x     = (const float*)d_in[0];
    const float* Wqkv  = (const float*)d_in[1];
    const float* bqkv  = (const float*)d_in[2];
    const float* Wproj = (const float*)d_in[3];
    const float* bproj = (const float*)d_in[4];
    float* out = (float*)d_out;    // reference output dtype = float32

    const size_t NQ  = (size_t)BATCH * HEADS * SEQ * HD;   // 6291456
    const size_t FULL_BYTES = NQ * 4 * 2 + NQ * 2 * 2;     // 75,497,472

    if (ws_size >= FULL_BYTES) {
        // ---- full pipeline: 3 dispatches, 72 MiB ws ----
        float* Qf = (float*)d_ws;
        float* Kf = Qf + NQ;
        unsigned short* Vb = (unsigned short*)(Kf + NQ);
        unsigned short* Ob = Vb + NQ;

        gemm_qkv_f32<<<dim3(QKV_COLS / 128, M_ROWS / 128), 256, 0, stream>>>(
            x, Wqkv, bqkv, Qf, Kf, Vb);
        attn_f32<<<dim3((BATCH * HEADS * SEQ) / 64), 64, 0, stream>>>(Qf, Kf, Vb, Ob);
        gemm_proj_f32<<<dim3(EMB / 128, M_ROWS / 128), 256, 0, stream>>>(
            Ob, Wproj, bproj, out);
    } else {
        // ---- per-batch pipeline: ~19.5 MiB ws ----
        const size_t NQb = (size_t)HEADS * SEQ * HD;       // 786432
        float* Qf = (float*)d_ws;                          // 3.0 MiB
        float* Kf = Qf + NQb;                              // 3.0 MiB
        unsigned short* Vb = (unsigned short*)(Kf + NQb);  // 1.5 MiB
        unsigned short* Ob = Vb + NQb;                     // 12 MiB (full)

        for (int bi = 0; bi < BATCH; ++bi) {
            const float* xb = x + (size_t)bi * SEQ * EMB;
            unsigned short* Obb = Ob + (size_t)bi * SEQ * EMB;
            gemm_qkv_f32<<<dim3(QKV_COLS / 128, SEQ / 128), 256, 0, stream>>>(
                xb, Wqkv, bqkv, Qf, Kf, Vb);
            attn_f32<<<dim3((HEADS * SEQ) / 64), 64, 0, stream>>>(Qf, Kf, Vb, Obb);
        }
        gemm_proj_f32<<<dim3(EMB / 128, M_ROWS / 128), 256, 0, stream>>>(
            Ob, Wproj, bproj, out);
    }
}

// Round 8
// 619.396 us; speedup vs baseline: 4.9126x; 4.9126x over previous
//
#include <hip/hip_runtime.h>
#include <hip/hip_bf16.h>
#include <stdint.h>

#define EMB 768
#define HEADS 12
#define BATCH 8
#define SEQ 1024
#define HD 64
#define M_ROWS (BATCH * SEQ)   /* 8192 */
#define QKV_COLS (3 * EMB)     /* 2304 */

typedef __attribute__((ext_vector_type(8))) short short8;
typedef __attribute__((ext_vector_type(4))) float f32x4;

__device__ __forceinline__ unsigned short f2bf(float x) {
    union { float f; unsigned u; } v; v.f = x;
    unsigned r = v.u + 0x7FFFu + ((v.u >> 16) & 1u);
    return (unsigned short)(r >> 16);
}
__device__ __forceinline__ float bf2f(unsigned short h) {
    union { unsigned u; float f; } v; v.u = ((unsigned)h) << 16;
    return v.f;
}

#define MFMA16(a, b, c) __builtin_amdgcn_mfma_f32_16x16x32_bf16((a), (b), (c), 0, 0, 0)

// ---------------------------------------------------------------------------
// QKV GEMM: X fp32 [8192x768] @ W fp32 [768x2304] + b, both operands split
// hi+lo bf16 (acc = AhBh + AhBl + AlBh; AlBl ~2^-18 dropped) -> near-fp32.
// Epilogue de-interleaves col c = 192h + 3d + which into Qh/Ql/Kh/Kl/Vb,
// each [B,H,N,D].  (Conventions validated by the passing r7 run.)
// ---------------------------------------------------------------------------
__global__ __launch_bounds__(256, 2)
void gemm_qkv(const float* __restrict__ X, const float* __restrict__ W,
              const float* __restrict__ bias,
              unsigned short* __restrict__ Qh, unsigned short* __restrict__ Ql,
              unsigned short* __restrict__ Kh, unsigned short* __restrict__ Kl,
              unsigned short* __restrict__ Vb)
{
    __shared__ unsigned short Ash[128][40], Asl[128][40];  // [row][k]
    __shared__ unsigned short Bsh[128][40], Bsl[128][40];  // [col][k] (B^T)

    const int tid  = threadIdx.x;
    const int wave = tid >> 6, lane = tid & 63;
    const int lr = lane & 15, lg = lane >> 4;
    const int wr = (wave >> 1) * 64, wc = (wave & 1) * 64;
    const int m0 = blockIdx.y * 128;
    const int c0 = blockIdx.x * 128;

    const f32x4 fzero = {0.f, 0.f, 0.f, 0.f};
    f32x4 acc[4][4];
    #pragma unroll
    for (int m = 0; m < 4; ++m)
        #pragma unroll
        for (int n = 0; n < 4; ++n) acc[m][n] = fzero;

    for (int k0 = 0; k0 < EMB; k0 += 32) {
        // A tile: 128 rows x 32 k (fp32) -> hi/lo bf16
        #pragma unroll
        for (int p = 0; p < 4; ++p) {
            int idx = (p << 8) + tid;
            int row = idx >> 3, kc = (idx & 7) << 2;
            f32x4 v = *reinterpret_cast<const f32x4*>(X + (size_t)(m0 + row) * EMB + k0 + kc);
            #pragma unroll
            for (int j = 0; j < 4; ++j) {
                const unsigned short hb = f2bf(v[j]);
                Ash[row][kc + j] = hb;
                Asl[row][kc + j] = f2bf(v[j] - bf2f(hb));
            }
        }
        // B tile: 32 k-rows x 128 cols (fp32) -> hi/lo bf16, transposed
        #pragma unroll
        for (int p = 0; p < 4; ++p) {
            int idx = (p << 8) + tid;
            int kk = idx >> 5, cc = (idx & 31) << 2;
            f32x4 v = *reinterpret_cast<const f32x4*>(W + (size_t)(k0 + kk) * QKV_COLS + c0 + cc);
            #pragma unroll
            for (int j = 0; j < 4; ++j) {
                const unsigned short hb = f2bf(v[j]);
                Bsh[cc + j][kk] = hb;
                Bsl[cc + j][kk] = f2bf(v[j] - bf2f(hb));
            }
        }
        __syncthreads();

        short8 ah[4], al[4], bh[4], bl[4];
        #pragma unroll
        for (int m = 0; m < 4; ++m) {
            ah[m] = *reinterpret_cast<const short8*>(&Ash[wr + m * 16 + lr][lg << 3]);
            al[m] = *reinterpret_cast<const short8*>(&Asl[wr + m * 16 + lr][lg << 3]);
        }
        #pragma unroll
        for (int n = 0; n < 4; ++n) {
            bh[n] = *reinterpret_cast<const short8*>(&Bsh[wc + n * 16 + lr][lg << 3]);
            bl[n] = *reinterpret_cast<const short8*>(&Bsl[wc + n * 16 + lr][lg << 3]);
        }
        #pragma unroll
        for (int m = 0; m < 4; ++m)
            #pragma unroll
            for (int n = 0; n < 4; ++n) {
                acc[m][n] = MFMA16(ah[m], bh[n], acc[m][n]);
                acc[m][n] = MFMA16(ah[m], bl[n], acc[m][n]);
                acc[m][n] = MFMA16(al[m], bh[n], acc[m][n]);
            }
        __syncthreads();
    }

    // epilogue: C/D layout col=lane&15, row=(lane>>4)*4+reg  [m89-verified]
    #pragma unroll
    for (int m = 0; m < 4; ++m) {
        #pragma unroll
        for (int n = 0; n < 4; ++n) {
            const int colg = c0 + wc + n * 16 + lr;
            const float bv = bias[colg];
            const int which = colg % 3;
            const int h  = colg / 192;
            const int dd = (colg % 192) / 3;
            #pragma unroll
            for (int j = 0; j < 4; ++j) {
                const int rowg = m0 + wr + m * 16 + (lg << 2) + j;
                const float val = acc[m][n][j] + bv;
                const int bi = rowg >> 10, ni = rowg & (SEQ - 1);
                const size_t oidx = (((size_t)bi * HEADS + h) * SEQ + ni) * HD + dd;
                if (which == 0) {
                    const unsigned short hb = f2bf(val);
                    Qh[oidx] = hb;
                    Ql[oidx] = f2bf(val - bf2f(hb));
                } else if (which == 1) {
                    const unsigned short hb = f2bf(val);
                    Kh[oidx] = hb;
                    Kl[oidx] = f2bf(val - bf2f(hb));
                } else {
                    Vb[oidx] = f2bf(val);
                }
            }
        }
    }
}

// ---------------------------------------------------------------------------
// Flash attention, one (b,h)x(64 q-rows) per block, 4 waves (16 rows each).
// Q,K pre-split hi+lo bf16 -> near-fp32 UNSCALED scores via
// S = Qh*Kh + Ql*Kh + Qh*Kl. Softmax first; /sqrt(768) folded into output.
// ---------------------------------------------------------------------------
__global__ __launch_bounds__(256, 2)
void attn_fused(const unsigned short* __restrict__ Qh, const unsigned short* __restrict__ Ql,
                const unsigned short* __restrict__ Kh, const unsigned short* __restrict__ Kl,
                const unsigned short* __restrict__ Vb,
                unsigned short* __restrict__ Ob)
{
    __shared__ unsigned short Vt[64][72];        // V^T tile: [d][key]
    __shared__ unsigned short Plds[4][16][72];   // per-wave P: [qrow][key]

    const int tid  = threadIdx.x;
    const int wave = tid >> 6, lane = tid & 63;
    const int lr = lane & 15, lg = lane >> 4;
    const int qt = blockIdx.x;          // 0..15
    const int bh = blockIdx.y;          // 0..95
    const int b = bh / HEADS, h = bh % HEADS;

    const size_t base = (size_t)bh * SEQ * HD;
    const unsigned short* Qhb = Qh + base;
    const unsigned short* Qlb = Ql + base;
    const unsigned short* Khb = Kh + base;
    const unsigned short* Klb = Kl + base;
    const unsigned short* Vbb = Vb + base;

    const int q0 = qt * 64 + wave * 16;

    // Q fragments (A-operand: lane holds row lr, k-elems kk*32 + lg*8 ..+7)
    short8 qh[2], ql[2];
    #pragma unroll
    for (int kk = 0; kk < 2; ++kk) {
        const size_t off = (size_t)(q0 + lr) * HD + kk * 32 + (lg << 3);
        qh[kk] = *reinterpret_cast<const short8*>(Qhb + off);
        ql[kk] = *reinterpret_cast<const short8*>(Qlb + off);
    }

    float mrow[4], lrow[4];
    f32x4 oacc[4];
    const f32x4 fzero = {0.f, 0.f, 0.f, 0.f};
    #pragma unroll
    for (int j = 0; j < 4; ++j) { mrow[j] = -1.0e30f; lrow[j] = 0.f; }
    #pragma unroll
    for (int d = 0; d < 4; ++d) oacc[d] = fzero;

    for (int t = 0; t < SEQ / 64; ++t) {
        const int kbase = t * 64;

        __syncthreads();                 // all waves done reading previous Vt
        #pragma unroll
        for (int p = 0; p < 2; ++p) {
            int idx = (p << 8) + tid;
            int r = idx >> 3, dc = (idx & 7) << 3;
            uint4 v = *reinterpret_cast<const uint4*>(Vbb + (size_t)(kbase + r) * HD + dc);
            const unsigned short* pv = reinterpret_cast<const unsigned short*>(&v);
            #pragma unroll
            for (int j = 0; j < 8; ++j) Vt[dc + j][r] = pv[j];
        }
        __syncthreads();

        // S = Q K^T over this 64-key tile (B-operand: lane holds key col lr)
        f32x4 s[4];
        #pragma unroll
        for (int n = 0; n < 4; ++n) s[n] = fzero;
        #pragma unroll
        for (int n = 0; n < 4; ++n) {
            #pragma unroll
            for (int kk = 0; kk < 2; ++kk) {
                const size_t koff = (size_t)(kbase + n * 16 + lr) * HD + kk * 32 + (lg << 3);
                const short8 kh = *reinterpret_cast<const short8*>(Khb + koff);
                const short8 kl = *reinterpret_cast<const short8*>(Klb + koff);
                s[n] = MFMA16(qh[kk], kh, s[n]);
                s[n] = MFMA16(ql[kk], kh, s[n]);
                s[n] = MFMA16(qh[kk], kl, s[n]);
            }
        }

        // online softmax: lg-group owns row (lg<<2)+j; 64 keys over 16 lanes x 4 regs
        #pragma unroll
        for (int j = 0; j < 4; ++j) {
            float tmax = fmaxf(fmaxf(s[0][j], s[1][j]), fmaxf(s[2][j], s[3][j]));
            #pragma unroll
            for (int off = 8; off >= 1; off >>= 1)
                tmax = fmaxf(tmax, __shfl_xor(tmax, off, 16));
            const float mnew = fmaxf(mrow[j], tmax);
            const float corr = __expf(mrow[j] - mnew);
            mrow[j] = mnew;
            float psum = 0.f;
            #pragma unroll
            for (int n = 0; n < 4; ++n) {
                const float p = __expf(s[n][j] - mnew);
                psum += p;
                Plds[wave][(lg << 2) + j][n * 16 + lr] = f2bf(p);
            }
            #pragma unroll
            for (int off = 8; off >= 1; off >>= 1)
                psum += __shfl_xor(psum, off, 16);
            lrow[j] = lrow[j] * corr + psum;
            #pragma unroll
            for (int d = 0; d < 4; ++d) oacc[d][j] *= corr;
        }

        // O += P V  (A = P from LDS; B = V^T so key is the contiguous k-dim)
        #pragma unroll
        for (int kk = 0; kk < 2; ++kk) {
            const short8 ap = *reinterpret_cast<const short8*>(&Plds[wave][lr][kk * 32 + (lg << 3)]);
            #pragma unroll
            for (int d = 0; d < 4; ++d) {
                const short8 bv = *reinterpret_cast<const short8*>(&Vt[d * 16 + lr][kk * 32 + (lg << 3)]);
                oacc[d] = MFMA16(ap, bv, oacc[d]);
            }
        }
    }

    // epilogue: O / l / sqrt(768); layout [b, n, h*64+dcol] -> [8192][768]
    const float rs = 0.036084391824351615f;  // 1/sqrt(768)
    #pragma unroll
    for (int j = 0; j < 4; ++j) {
        const float sc = rs / lrow[j];
        const int q = q0 + (lg << 2) + j;
        #pragma unroll
        for (int d = 0; d < 4; ++d) {
            const float val = oacc[d][j] * sc;
            Ob[((size_t)b * SEQ + q) * EMB + h * HD + d * 16 + lr] = f2bf(val);
        }
    }
}

// ---------------------------------------------------------------------------
// Proj GEMM (MFMA): Ob bf16 [8192x768] @ W_proj (fp32 -> bf16) + b
// -> fp32 d_out.
// ---------------------------------------------------------------------------
__global__ __launch_bounds__(256, 2)
void gemm_proj(const unsigned short* __restrict__ A, const float* __restrict__ W,
               const float* __restrict__ bias, float* __restrict__ Out)
{
    __shared__ unsigned short As[128][40];
    __shared__ unsigned short Bs[128][40];

    const int tid  = threadIdx.x;
    const int wave = tid >> 6, lane = tid & 63;
    const int lr = lane & 15, lg = lane >> 4;
    const int wr = (wave >> 1) * 64, wc = (wave & 1) * 64;
    const int m0 = blockIdx.y * 128;
    const int c0 = blockIdx.x * 128;

    const f32x4 fzero = {0.f, 0.f, 0.f, 0.f};
    f32x4 acc[4][4];
    #pragma unroll
    for (int m = 0; m < 4; ++m)
        #pragma unroll
        for (int n = 0; n < 4; ++n) acc[m][n] = fzero;

    for (int k0 = 0; k0 < EMB; k0 += 32) {
        #pragma unroll
        for (int p = 0; p < 2; ++p) {
            int idx = (p << 8) + tid;
            int row = idx >> 2, kc = (idx & 3) << 3;
            uint4 v = *reinterpret_cast<const uint4*>(A + (size_t)(m0 + row) * EMB + k0 + kc);
            *reinterpret_cast<uint4*>(&As[row][kc]) = v;
        }
        #pragma unroll
        for (int p = 0; p < 4; ++p) {
            int idx = (p << 8) + tid;
            int kk = idx >> 5, cc = (idx & 31) << 2;
            f32x4 v = *reinterpret_cast<const f32x4*>(W + (size_t)(k0 + kk) * EMB + c0 + cc);
            #pragma unroll
            for (int j = 0; j < 4; ++j) Bs[cc + j][kk] = f2bf(v[j]);
        }
        __syncthreads();

        short8 a[4], b[4];
        #pragma unroll
        for (int m = 0; m < 4; ++m)
            a[m] = *reinterpret_cast<const short8*>(&As[wr + m * 16 + lr][lg << 3]);
        #pragma unroll
        for (int n = 0; n < 4; ++n)
            b[n] = *reinterpret_cast<const short8*>(&Bs[wc + n * 16 + lr][lg << 3]);
        #pragma unroll
        for (int m = 0; m < 4; ++m)
            #pragma unroll
            for (int n = 0; n < 4; ++n)
                acc[m][n] = MFMA16(a[m], b[n], acc[m][n]);
        __syncthreads();
    }

    #pragma unroll
    for (int m = 0; m < 4; ++m) {
        #pragma unroll
        for (int n = 0; n < 4; ++n) {
            const int colg = c0 + wc + n * 16 + lr;
            const float bv = bias[colg];
            #pragma unroll
            for (int j = 0; j < 4; ++j) {
                const int rowg = m0 + wr + m * 16 + (lg << 2) + j;
                Out[(size_t)rowg * EMB + colg] = acc[m][n][j] + bv;   // fp32 out
            }
        }
    }
}

// ---------------------------------------------------------------------------
extern "C" void kernel_launch(void* const* d_in, const int* in_sizes, int n_in,
                              void* d_out, int out_size, void* d_ws, size_t ws_size,
                              hipStream_t stream)
{
    const float* x     = (const float*)d_in[0];
    const float* Wqkv  = (const float*)d_in[1];
    const float* bqkv  = (const float*)d_in[2];
    const float* Wproj = (const float*)d_in[3];
    const float* bproj = (const float*)d_in[4];
    float* out = (float*)d_out;    // reference output dtype = float32

    const size_t NQ = (size_t)BATCH * HEADS * SEQ * HD;  // 6291456
    unsigned short* Qh = (unsigned short*)d_ws;          // 12.6 MB each
    unsigned short* Ql = Qh + NQ;
    unsigned short* Kh = Ql + NQ;
    unsigned short* Kl = Kh + NQ;
    unsigned short* Vb = Kl + NQ;
    unsigned short* Ob = Vb + NQ;                        // total 75.5 MB (fits: r7 ran full path)

    gemm_qkv<<<dim3(QKV_COLS / 128, M_ROWS / 128), 256, 0, stream>>>(
        x, Wqkv, bqkv, Qh, Ql, Kh, Kl, Vb);
    attn_fused<<<dim3(SEQ / 64, BATCH * HEADS), 256, 0, stream>>>(Qh, Ql, Kh, Kl, Vb, Ob);
    gemm_proj<<<dim3(EMB / 128, M_ROWS / 128), 256, 0, stream>>>(
        Ob, Wproj, bproj, out);
}

// Round 9
// 395.773 us; speedup vs baseline: 7.6884x; 1.5650x over previous
//
#include <hip/hip_runtime.h>
#include <hip/hip_bf16.h>
#include <stdint.h>

#define EMB 768
#define HEADS 12
#define BATCH 8
#define SEQ 1024
#define HD 64
#define M_ROWS (BATCH * SEQ)   /* 8192 */
#define QKV_COLS (3 * EMB)     /* 2304 */

typedef __attribute__((ext_vector_type(8))) short short8;
typedef __attribute__((ext_vector_type(4))) float f32x4;

__device__ __forceinline__ unsigned short f2bf(float x) {
    union { float f; unsigned u; } v; v.f = x;
    unsigned r = v.u + 0x7FFFu + ((v.u >> 16) & 1u);
    return (unsigned short)(r >> 16);
}
__device__ __forceinline__ float bf2f(unsigned short h) {
    union { unsigned u; float f; } v; v.u = ((unsigned)h) << 16;
    return v.f;
}
// truncation split helpers (hi = top 16 bits; lo = x - hi, truncated)
__device__ __forceinline__ float truncbf(float x) {
    return __uint_as_float(__float_as_uint(x) & 0xFFFF0000u);
}
__device__ __forceinline__ uint32_t packtr(float a, float b) {   // lo16=tr(a), hi16=tr(b)
    return (__float_as_uint(a) >> 16) | (__float_as_uint(b) & 0xFFFF0000u);
}

#define MFMA16(a, b, c) __builtin_amdgcn_mfma_f32_16x16x32_bf16((a), (b), (c), 0, 0, 0)

// ---------------------------------------------------------------------------
// QKV GEMM: X fp32 [8192x768] @ W fp32 [768x2304] + b, both operands
// truncation-split hi+lo bf16 (acc = AhBh + AhBl + AlBh; AlBl ~2^-16 dropped).
// Staging: A packed-pair b64 writes; B register-transpose b64 writes
// (kg-inner lane assignment -> ~4-way banks instead of 16-way).
// MFMA core + epilogue identical to the r8-verified kernel.
// ---------------------------------------------------------------------------
__global__ __launch_bounds__(256, 2)
void gemm_qkv(const float* __restrict__ X, const float* __restrict__ W,
              const float* __restrict__ bias,
              unsigned short* __restrict__ Qh, unsigned short* __restrict__ Ql,
              unsigned short* __restrict__ Kh, unsigned short* __restrict__ Kl,
              unsigned short* __restrict__ Vb)
{
    __shared__ unsigned short Ash[128][40], Asl[128][40];  // [row][k]
    __shared__ unsigned short Bsh[128][40], Bsl[128][40];  // [col][k] (B^T)

    const int tid  = threadIdx.x;
    const int wave = tid >> 6, lane = tid & 63;
    const int lr = lane & 15, lg = lane >> 4;
    const int wr = (wave >> 1) * 64, wc = (wave & 1) * 64;
    const int m0 = blockIdx.y * 128;
    const int c0 = blockIdx.x * 128;

    const f32x4 fzero = {0.f, 0.f, 0.f, 0.f};
    f32x4 acc[4][4];
    #pragma unroll
    for (int m = 0; m < 4; ++m)
        #pragma unroll
        for (int n = 0; n < 4; ++n) acc[m][n] = fzero;

    const int kgB = tid & 7;        // B-staging: 8 k-groups of 4
    const int cgB = tid >> 3;       // 32 col-groups of 4

    for (int k0 = 0; k0 < EMB; k0 += 32) {
        // A tile: 128 rows x 32 k; thread packs 4 consecutive k -> b64 hi + b64 lo
        #pragma unroll
        for (int p = 0; p < 4; ++p) {
            int idx = (p << 8) + tid;
            int row = idx >> 3, kc = (idx & 7) << 2;
            f32x4 v = *reinterpret_cast<const f32x4*>(X + (size_t)(m0 + row) * EMB + k0 + kc);
            float l0 = v[0] - truncbf(v[0]), l1 = v[1] - truncbf(v[1]);
            float l2 = v[2] - truncbf(v[2]), l3 = v[3] - truncbf(v[3]);
            uint2 hw = { packtr(v[0], v[1]), packtr(v[2], v[3]) };
            uint2 lw = { packtr(l0, l1), packtr(l2, l3) };
            *reinterpret_cast<uint2*>(&Ash[row][kc]) = hw;
            *reinterpret_cast<uint2*>(&Asl[row][kc]) = lw;
        }
        // B tile: 32 k x 128 cols; register transpose 4x4, b64 writes per col
        {
            f32x4 v[4];
            #pragma unroll
            for (int i = 0; i < 4; ++i)
                v[i] = *reinterpret_cast<const f32x4*>(
                    W + (size_t)(k0 + kgB * 4 + i) * QKV_COLS + c0 + cgB * 4);
            #pragma unroll
            for (int j = 0; j < 4; ++j) {
                float a0 = v[0][j], a1 = v[1][j], a2 = v[2][j], a3 = v[3][j];
                float b0 = a0 - truncbf(a0), b1 = a1 - truncbf(a1);
                float b2 = a2 - truncbf(a2), b3 = a3 - truncbf(a3);
                uint2 hw = { packtr(a0, a1), packtr(a2, a3) };
                uint2 lw = { packtr(b0, b1), packtr(b2, b3) };
                *reinterpret_cast<uint2*>(&Bsh[cgB * 4 + j][kgB * 4]) = hw;
                *reinterpret_cast<uint2*>(&Bsl[cgB * 4 + j][kgB * 4]) = lw;
            }
        }
        __syncthreads();

        short8 ah[4], al[4], bh[4], bl[4];
        #pragma unroll
        for (int m = 0; m < 4; ++m) {
            ah[m] = *reinterpret_cast<const short8*>(&Ash[wr + m * 16 + lr][lg << 3]);
            al[m] = *reinterpret_cast<const short8*>(&Asl[wr + m * 16 + lr][lg << 3]);
        }
        #pragma unroll
        for (int n = 0; n < 4; ++n) {
            bh[n] = *reinterpret_cast<const short8*>(&Bsh[wc + n * 16 + lr][lg << 3]);
            bl[n] = *reinterpret_cast<const short8*>(&Bsl[wc + n * 16 + lr][lg << 3]);
        }
        #pragma unroll
        for (int m = 0; m < 4; ++m)
            #pragma unroll
            for (int n = 0; n < 4; ++n) {
                acc[m][n] = MFMA16(ah[m], bh[n], acc[m][n]);
                acc[m][n] = MFMA16(ah[m], bl[n], acc[m][n]);
                acc[m][n] = MFMA16(al[m], bh[n], acc[m][n]);
            }
        __syncthreads();
    }

    // epilogue: C/D layout col=lane&15, row=(lane>>4)*4+reg  [r8-verified]
    #pragma unroll
    for (int m = 0; m < 4; ++m) {
        #pragma unroll
        for (int n = 0; n < 4; ++n) {
            const int colg = c0 + wc + n * 16 + lr;
            const float bv = bias[colg];
            const int which = colg % 3;
            const int h  = colg / 192;
            const int dd = (colg % 192) / 3;
            #pragma unroll
            for (int j = 0; j < 4; ++j) {
                const int rowg = m0 + wr + m * 16 + (lg << 2) + j;
                const float val = acc[m][n][j] + bv;
                const int bi = rowg >> 10, ni = rowg & (SEQ - 1);
                const size_t oidx = (((size_t)bi * HEADS + h) * SEQ + ni) * HD + dd;
                if (which == 0) {
                    const uint32_t uv = __float_as_uint(val);
                    Qh[oidx] = (unsigned short)(uv >> 16);
                    Ql[oidx] = (unsigned short)(__float_as_uint(
                        val - __uint_as_float(uv & 0xFFFF0000u)) >> 16);
                } else if (which == 1) {
                    const uint32_t uv = __float_as_uint(val);
                    Kh[oidx] = (unsigned short)(uv >> 16);
                    Kl[oidx] = (unsigned short)(__float_as_uint(
                        val - __uint_as_float(uv & 0xFFFF0000u)) >> 16);
                } else {
                    Vb[oidx] = f2bf(val);   // RN for V
                }
            }
        }
    }
}

// ---------------------------------------------------------------------------
// Flash attention (identical to r8-verified): one (b,h)x64 q-rows per block,
// 4 waves x 16 rows. S = Qh*Kh + Ql*Kh + Qh*Kl (unscaled); softmax first;
// /sqrt(768) folded into output scale.
// ---------------------------------------------------------------------------
__global__ __launch_bounds__(256, 2)
void attn_fused(const unsigned short* __restrict__ Qh, const unsigned short* __restrict__ Ql,
                const unsigned short* __restrict__ Kh, const unsigned short* __restrict__ Kl,
                const unsigned short* __restrict__ Vb,
                unsigned short* __restrict__ Ob)
{
    __shared__ unsigned short Vt[64][72];        // V^T tile: [d][key]
    __shared__ unsigned short Plds[4][16][72];   // per-wave P: [qrow][key]

    const int tid  = threadIdx.x;
    const int wave = tid >> 6, lane = tid & 63;
    const int lr = lane & 15, lg = lane >> 4;
    const int qt = blockIdx.x;          // 0..15
    const int bh = blockIdx.y;          // 0..95
    const int b = bh / HEADS, h = bh % HEADS;

    const size_t base = (size_t)bh * SEQ * HD;
    const unsigned short* Qhb = Qh + base;
    const unsigned short* Qlb = Ql + base;
    const unsigned short* Khb = Kh + base;
    const unsigned short* Klb = Kl + base;
    const unsigned short* Vbb = Vb + base;

    const int q0 = qt * 64 + wave * 16;

    short8 qh[2], ql[2];
    #pragma unroll
    for (int kk = 0; kk < 2; ++kk) {
        const size_t off = (size_t)(q0 + lr) * HD + kk * 32 + (lg << 3);
        qh[kk] = *reinterpret_cast<const short8*>(Qhb + off);
        ql[kk] = *reinterpret_cast<const short8*>(Qlb + off);
    }

    float mrow[4], lrow[4];
    f32x4 oacc[4];
    const f32x4 fzero = {0.f, 0.f, 0.f, 0.f};
    #pragma unroll
    for (int j = 0; j < 4; ++j) { mrow[j] = -1.0e30f; lrow[j] = 0.f; }
    #pragma unroll
    for (int d = 0; d < 4; ++d) oacc[d] = fzero;

    for (int t = 0; t < SEQ / 64; ++t) {
        const int kbase = t * 64;

        __syncthreads();
        #pragma unroll
        for (int p = 0; p < 2; ++p) {
            int idx = (p << 8) + tid;
            int r = idx >> 3, dc = (idx & 7) << 3;
            uint4 v = *reinterpret_cast<const uint4*>(Vbb + (size_t)(kbase + r) * HD + dc);
            const unsigned short* pv = reinterpret_cast<const unsigned short*>(&v);
            #pragma unroll
            for (int j = 0; j < 8; ++j) Vt[dc + j][r] = pv[j];
        }
        __syncthreads();

        f32x4 s[4];
        #pragma unroll
        for (int n = 0; n < 4; ++n) s[n] = fzero;
        #pragma unroll
        for (int n = 0; n < 4; ++n) {
            #pragma unroll
            for (int kk = 0; kk < 2; ++kk) {
                const size_t koff = (size_t)(kbase + n * 16 + lr) * HD + kk * 32 + (lg << 3);
                const short8 kh = *reinterpret_cast<const short8*>(Khb + koff);
                const short8 kl = *reinterpret_cast<const short8*>(Klb + koff);
                s[n] = MFMA16(qh[kk], kh, s[n]);
                s[n] = MFMA16(ql[kk], kh, s[n]);
                s[n] = MFMA16(qh[kk], kl, s[n]);
            }
        }

        #pragma unroll
        for (int j = 0; j < 4; ++j) {
            float tmax = fmaxf(fmaxf(s[0][j], s[1][j]), fmaxf(s[2][j], s[3][j]));
            #pragma unroll
            for (int off = 8; off >= 1; off >>= 1)
                tmax = fmaxf(tmax, __shfl_xor(tmax, off, 16));
            const float mnew = fmaxf(mrow[j], tmax);
            const float corr = __expf(mrow[j] - mnew);
            mrow[j] = mnew;
            float psum = 0.f;
            #pragma unroll
            for (int n = 0; n < 4; ++n) {
                const float p = __expf(s[n][j] - mnew);
                psum += p;
                Plds[wave][(lg << 2) + j][n * 16 + lr] = f2bf(p);
            }
            #pragma unroll
            for (int off = 8; off >= 1; off >>= 1)
                psum += __shfl_xor(psum, off, 16);
            lrow[j] = lrow[j] * corr + psum;
            #pragma unroll
            for (int d = 0; d < 4; ++d) oacc[d][j] *= corr;
        }

        #pragma unroll
        for (int kk = 0; kk < 2; ++kk) {
            const short8 ap = *reinterpret_cast<const short8*>(&Plds[wave][lr][kk * 32 + (lg << 3)]);
            #pragma unroll
            for (int d = 0; d < 4; ++d) {
                const short8 bv = *reinterpret_cast<const short8*>(&Vt[d * 16 + lr][kk * 32 + (lg << 3)]);
                oacc[d] = MFMA16(ap, bv, oacc[d]);
            }
        }
    }

    const float rs = 0.036084391824351615f;  // 1/sqrt(768)
    #pragma unroll
    for (int j = 0; j < 4; ++j) {
        const float sc = rs / lrow[j];
        const int q = q0 + (lg << 2) + j;
        #pragma unroll
        for (int d = 0; d < 4; ++d) {
            const float val = oacc[d][j] * sc;
            Ob[((size_t)b * SEQ + q) * EMB + h * HD + d * 16 + lr] = f2bf(val);
        }
    }
}

// ---------------------------------------------------------------------------
// Proj GEMM (MFMA): Ob bf16 [8192x768] @ W_proj (fp32 -> bf16 RN) + b
// -> fp32 d_out. B staging via register transpose (conflict fix).
// ---------------------------------------------------------------------------
__global__ __launch_bounds__(256, 2)
void gemm_proj(const unsigned short* __restrict__ A, const float* __restrict__ W,
               const float* __restrict__ bias, float* __restrict__ Out)
{
    __shared__ unsigned short As[128][40];
    __shared__ unsigned short Bs[128][40];

    const int tid  = threadIdx.x;
    const int wave = tid >> 6, lane = tid & 63;
    const int lr = lane & 15, lg = lane >> 4;
    const int wr = (wave >> 1) * 64, wc = (wave & 1) * 64;
    const int m0 = blockIdx.y * 128;
    const int c0 = blockIdx.x * 128;

    const f32x4 fzero = {0.f, 0.f, 0.f, 0.f};
    f32x4 acc[4][4];
    #pragma unroll
    for (int m = 0; m < 4; ++m)
        #pragma unroll
        for (int n = 0; n < 4; ++n) acc[m][n] = fzero;

    const int kgB = tid & 7, cgB = tid >> 3;

    for (int k0 = 0; k0 < EMB; k0 += 32) {
        #pragma unroll
        for (int p = 0; p < 2; ++p) {
            int idx = (p << 8) + tid;
            int row = idx >> 2, kc = (idx & 3) << 3;
            uint4 v = *reinterpret_cast<const uint4*>(A + (size_t)(m0 + row) * EMB + k0 + kc);
            *reinterpret_cast<uint4*>(&As[row][kc]) = v;
        }
        {
            f32x4 v[4];
            #pragma unroll
            for (int i = 0; i < 4; ++i)
                v[i] = *reinterpret_cast<const f32x4*>(
                    W + (size_t)(k0 + kgB * 4 + i) * EMB + c0 + cgB * 4);
            #pragma unroll
            for (int j = 0; j < 4; ++j) {
                uint2 w = { (uint32_t)f2bf(v[0][j]) | ((uint32_t)f2bf(v[1][j]) << 16),
                            (uint32_t)f2bf(v[2][j]) | ((uint32_t)f2bf(v[3][j]) << 16) };
                *reinterpret_cast<uint2*>(&Bs[cgB * 4 + j][kgB * 4]) = w;
            }
        }
        __syncthreads();

        short8 a[4], b[4];
        #pragma unroll
        for (int m = 0; m < 4; ++m)
            a[m] = *reinterpret_cast<const short8*>(&As[wr + m * 16 + lr][lg << 3]);
        #pragma unroll
        for (int n = 0; n < 4; ++n)
            b[n] = *reinterpret_cast<const short8*>(&Bs[wc + n * 16 + lr][lg << 3]);
        #pragma unroll
        for (int m = 0; m < 4; ++m)
            #pragma unroll
            for (int n = 0; n < 4; ++n)
                acc[m][n] = MFMA16(a[m], b[n], acc[m][n]);
        __syncthreads();
    }

    #pragma unroll
    for (int m = 0; m < 4; ++m) {
        #pragma unroll
        for (int n = 0; n < 4; ++n) {
            const int colg = c0 + wc + n * 16 + lr;
            const float bv = bias[colg];
            #pragma unroll
            for (int j = 0; j < 4; ++j) {
                const int rowg = m0 + wr + m * 16 + (lg << 2) + j;
                Out[(size_t)rowg * EMB + colg] = acc[m][n][j] + bv;   // fp32 out
            }
        }
    }
}

// ---------------------------------------------------------------------------
extern "C" void kernel_launch(void* const* d_in, const int* in_sizes, int n_in,
                              void* d_out, int out_size, void* d_ws, size_t ws_size,
                              hipStream_t stream)
{
    const float* x     = (const float*)d_in[0];
    const float* Wqkv  = (const float*)d_in[1];
    const float* bqkv  = (const float*)d_in[2];
    const float* Wproj = (const float*)d_in[3];
    const float* bproj = (const float*)d_in[4];
    float* out = (float*)d_out;    // reference output dtype = float32

    const size_t NQ = (size_t)BATCH * HEADS * SEQ * HD;  // 6291456
    unsigned short* Qh = (unsigned short*)d_ws;
    unsigned short* Ql = Qh + NQ;
    unsigned short* Kh = Ql + NQ;
    unsigned short* Kl = Kh + NQ;
    unsigned short* Vb = Kl + NQ;
    unsigned short* Ob = Vb + NQ;                        // total 75.5 MB

    gemm_qkv<<<dim3(QKV_COLS / 128, M_ROWS / 128), 256, 0, stream>>>(
        x, Wqkv, bqkv, Qh, Ql, Kh, Kl, Vb);
    attn_fused<<<dim3(SEQ / 64, BATCH * HEADS), 256, 0, stream>>>(Qh, Ql, Kh, Kl, Vb, Ob);
    gemm_proj<<<dim3(EMB / 128, M_ROWS / 128), 256, 0, stream>>>(
        Ob, Wproj, bproj, out);
}